// Round 4
// baseline (600.321 us; speedup 1.0000x reference)
//
#include <hip/hip_runtime.h>
#include <math.h>

// ---------------- workspace layout (float offsets) ----------------
#define WS_X1    0                    // 16384*200
#define WS_WPAD  3276800              // 200*256
#define WS_W2T   3328000              // 1024*1600  [n][c*40+o]
#define WS_AS    4966400              // 1024
#define WS_AD    4967424              // 1024
#define WS_MAXS  4968448              // 16
#define WS_WEFF  4968464              // 40*30
#define WS_S1    4969664              // 40
#define WS_SH1   4969704              // 40
#define WS_S2    4969744              // 40
#define WS_SH2   4969784              // 40
#define WS_H     4970496              // 1024*256
#define WS_P     5232640              // 1024*1024 normalized softmax P
#define WS_AP    6281216              // 8*1024*256 attention split-K partials
#define WS_Y3P   WS_P                 // 16*64*1400 (overlays P+AP head; both dead by k3)
#define WS_Y4    8378368              // 16*1400
#define WS_Y5    8400768              // 16*1400
#define WS_Z     8423168              // 16*1024
#define WS_G     8439552              // 16*1024
#define WS_ZP    8455936              // 7*16*1024
#define WS_Z2P   8570624              // 8*16*1024
// end 8,701,696 floats = 34.8 MB (< 36.7 MB proven)

// ---------------- k0: parameter prep ----------------
__global__ __launch_bounds__(256) void k0_prep(const float* __restrict__ gat_W,
                        const float* __restrict__ conv1_w, const float* __restrict__ conv1_b,
                        const float* __restrict__ bn1_g, const float* __restrict__ bn1_b,
                        const float* __restrict__ bn1_m, const float* __restrict__ bn1_v,
                        const float* __restrict__ conv2_b,
                        const float* __restrict__ bn2_g, const float* __restrict__ bn2_b,
                        const float* __restrict__ bn2_m, const float* __restrict__ bn2_v,
                        float* __restrict__ ws) {
  int bx = blockIdx.x, t = threadIdx.x;
  if (bx < 200) {
    ws[WS_WPAD + bx * 256 + t] = (t < 200) ? gat_W[bx * 200 + t] : 0.f;
    return;
  }
  if (t < 40) {
    float* weff = ws + WS_WEFF;
    for (int j = 0; j < 30; ++j) {
      float s = 0.f;
      for (int tt = 0; tt < 5; ++tt) {
        int k = j - tt;
        if (k >= 0 && k < 26) s += conv1_w[t * 26 + k];
      }
      weff[t * 30 + j] = s * 0.2f;
    }
    float s1 = bn1_g[t] * rsqrtf(bn1_v[t] + 1e-5f);
    ws[WS_S1 + t] = s1;
    ws[WS_SH1 + t] = bn1_b[t] + (conv1_b[t] - bn1_m[t]) * s1;
    float s2 = bn2_g[t] * rsqrtf(bn2_v[t] + 1e-5f);
    ws[WS_S2 + t] = s2;
    ws[WS_SH2 + t] = bn2_b[t] + (conv2_b[t] - bn2_m[t]) * s2;
  }
}

// ---------------- k0b: LDS tile transpose conv2_w (o,c,n) -> w2t[n][c*40+o] ----------------
__global__ __launch_bounds__(256) void k0b_w2t(const float* __restrict__ w2,
                                               float* __restrict__ w2t) {
  __shared__ float tile[32][65];
  int jt = blockIdx.x * 32;    // j = c*40+o, 50 tiles
  int n0 = blockIdx.y * 64;    // 16 tiles
  int t = threadIdx.x;
  for (int i = t; i < 2048; i += 256) {
    int jr = i >> 6, n = i & 63;
    int j = jt + jr;
    int o = j % 40, c = j / 40;
    tile[jr][n] = w2[(o * 40 + c) * 1024 + n0 + n];
  }
  __syncthreads();
  for (int i = t; i < 2048; i += 256) {
    int nr = i >> 5, j = i & 31;
    w2t[(n0 + nr) * 1600 + jt + j] = tile[j][nr];
  }
}

// ---------------- k1: h = x @ wpad; rows>=1024 fused into x1 ----------------
__global__ __launch_bounds__(256) void k1_gemm_h(const float* __restrict__ x,
                                                 const float* __restrict__ wpad,
                                                 const float* __restrict__ gat_b,
                                                 float* __restrict__ h,
                                                 float* __restrict__ x1) {
  __shared__ __align__(16) float As[8][64];
  __shared__ __align__(16) float Bs[8][64];
  int t = threadIdx.x;
  int tm = t & 15, tn = t >> 4;
  int row0 = blockIdx.x * 64;
  int col0 = blockIdx.y * 64;
  float acc[4][4] = {};
  for (int k0 = 0; k0 < 200; k0 += 8) {
    for (int i = t; i < 512; i += 256) {
      int m = i >> 3, k = i & 7;
      As[k][m] = x[(row0 + m) * 200 + k0 + k];
    }
    for (int i = t; i < 512; i += 256) {
      int k = i >> 6, n = i & 63;
      Bs[k][n] = wpad[(k0 + k) * 256 + col0 + n];
    }
    __syncthreads();
#pragma unroll
    for (int k = 0; k < 8; ++k) {
      float4 a = *(const float4*)&As[k][tm * 4];
      float4 bq = *(const float4*)&Bs[k][tn * 4];
      float av[4] = {a.x, a.y, a.z, a.w};
      float bv[4] = {bq.x, bq.y, bq.z, bq.w};
#pragma unroll
      for (int i = 0; i < 4; ++i)
#pragma unroll
        for (int j = 0; j < 4; ++j) acc[i][j] += av[i] * bv[j];
    }
    __syncthreads();
  }
  if (row0 < 1024) {
#pragma unroll
    for (int i = 0; i < 4; ++i)
#pragma unroll
      for (int j = 0; j < 4; ++j)
        h[(row0 + tm * 4 + i) * 256 + col0 + tn * 4 + j] = acc[i][j];
  } else {
    int col = col0 + tn * 4;
    if (col < 200) {
      float4 gb = *(const float4*)(gat_b + col);
#pragma unroll
      for (int i = 0; i < 4; ++i) {
        int row = row0 + tm * 4 + i;
        float4 xv = *(const float4*)(x + row * 200 + col);
        float4 o;
        o.x = xv.x + acc[i][0] + gb.x;
        o.y = xv.y + acc[i][1] + gb.y;
        o.z = xv.z + acc[i][2] + gb.z;
        o.w = xv.w + acc[i][3] + gb.w;
        *(float4*)(x1 + row * 200 + col) = o;
      }
    }
  }
}

// ---------------- k1b: attention scores ----------------
__global__ void k1b_scores(const float* __restrict__ h, const float* __restrict__ att_src,
                           const float* __restrict__ att_dst, float* __restrict__ as_,
                           float* __restrict__ ad_) {
  int r = blockIdx.x * 256 + threadIdx.x;
  const float* hr = h + r * 256;
  float s = 0.f, d = 0.f;
  for (int f = 0; f < 200; ++f) {
    float v = hr[f];
    s += v * att_src[f];
    d += v * att_dst[f];
  }
  as_[r] = s;
  ad_[r] = d;
}

// ---------------- k1c: max over a_s ----------------
__global__ void k1c_max(const float* __restrict__ as_, float* __restrict__ maxs) {
  __shared__ float rb[256];
  int t = threadIdx.x;
  float m = -1e30f;
  for (int j = t; j < 1024; j += 256) m = fmaxf(m, as_[j]);
  rb[t] = m;
  __syncthreads();
  for (int s = 128; s > 0; s >>= 1) {
    if (t < s) rb[t] = fmaxf(rb[t], rb[t + s]);
    __syncthreads();
  }
  if (t == 0) maxs[0] = rb[0];
}

// ---------------- kP: normalized softmax P ----------------
__global__ __launch_bounds__(256) void kP(const float* __restrict__ as_,
                                          const float* __restrict__ ad_,
                                          const float* __restrict__ maxs_p,
                                          float* __restrict__ P) {
  __shared__ float rb[256];
  int t = threadIdx.x, i = blockIdx.x;
  float ad = ad_[i];
  float mv = maxs_p[0] + ad;
  float M = mv >= 0.f ? mv : 0.2f * mv;
  float p[4];
  float s = 0.f;
#pragma unroll
  for (int q = 0; q < 4; ++q) {
    float v = as_[q * 256 + t] + ad;
    float l = v >= 0.f ? v : 0.2f * v;
    p[q] = __expf(l - M);
    s += p[q];
  }
  rb[t] = s;
  __syncthreads();
  for (int st = 128; st > 0; st >>= 1) {
    if (t < st) rb[t] += rb[t + st];
    __syncthreads();
  }
  float inv = 1.f / rb[0];
#pragma unroll
  for (int q = 0; q < 4; ++q) P[i * 1024 + q * 256 + t] = p[q] * inv;
}

// ---------------- kAttn: split-K GEMM out0 = P @ h (8 K-chunks) ----------------
__global__ __launch_bounds__(256) void kAttn(const float* __restrict__ P,
                                             const float* __restrict__ h,
                                             float* __restrict__ ap) {
  __shared__ __align__(16) float As[8][64];
  __shared__ __align__(16) float Bs[8][64];
  int t = threadIdx.x;
  int tm = t & 15, tn = t >> 4;
  int i0 = blockIdx.x * 64, f0 = blockIdx.y * 64, j0 = blockIdx.z * 128;
  float acc[4][4] = {};
  for (int k0 = 0; k0 < 128; k0 += 8) {
    for (int i = t; i < 512; i += 256) {
      int m = i >> 3, k = i & 7;
      As[k][m] = P[(i0 + m) * 1024 + j0 + k0 + k];
    }
    for (int i = t; i < 512; i += 256) {
      int k = i >> 6, n = i & 63;
      Bs[k][n] = h[(j0 + k0 + k) * 256 + f0 + n];
    }
    __syncthreads();
#pragma unroll
    for (int k = 0; k < 8; ++k) {
      float4 a = *(const float4*)&As[k][tm * 4];
      float4 bq = *(const float4*)&Bs[k][tn * 4];
      float av[4] = {a.x, a.y, a.z, a.w};
      float bv[4] = {bq.x, bq.y, bq.z, bq.w};
#pragma unroll
      for (int i = 0; i < 4; ++i)
#pragma unroll
        for (int j = 0; j < 4; ++j) acc[i][j] += av[i] * bv[j];
    }
    __syncthreads();
  }
#pragma unroll
  for (int i = 0; i < 4; ++i) {
    int r = i0 + tm * 4 + i;
    float4 v = make_float4(acc[i][0], acc[i][1], acc[i][2], acc[i][3]);
    *(float4*)&ap[(blockIdx.z * 1024 + r) * 256 + f0 + tn * 4] = v;
  }
}

// ---------------- kAttnRed: reduce 8 partials + residual -> x1 rows [0,1024) ----------------
__global__ __launch_bounds__(256) void kAttnRed(const float* __restrict__ ap,
                                                const float* __restrict__ x,
                                                const float* __restrict__ gat_b,
                                                float* __restrict__ x1) {
  int t = threadIdx.x, r = blockIdx.x;
  if (t >= 200) return;
  float s = 0.f;
#pragma unroll
  for (int z = 0; z < 8; ++z) s += ap[(z * 1024 + r) * 256 + t];
  x1[r * 200 + t] = x[r * 200 + t] + s + gat_b[t];
}

// ---------------- k3: fused conv1+bn1+elu+conv2; 2 nodes/iter, high TLP ----------------
// grid (16 b, 64 nt), block 320. Each block: 16 nodes, 8 iters x 2 nodes.
// LDS 44.8 KB -> 3 blocks/CU (VGPR-bound at 128).
__global__ __launch_bounds__(320, 4) void k3_conv(const float* __restrict__ x1,
                                                  const float* __restrict__ w2t,
                                                  const float* __restrict__ ws,
                                                  float* __restrict__ y3p) {
  __shared__ __align__(16) float xbp[2][640];   // dbuf: 2 nodes x 40 windows x 8
  __shared__ __align__(16) float w2s[3200];     // 2 node rows of w2t
  __shared__ __align__(16) float tmpP[6728];    // 2 x 3364, stride 84/12 conflict-padded
  int t = threadIdx.x;
  int b = blockIdx.x, nt = blockIdx.y;
  int base_n = nt * 16;
  int c1 = t / 7, wg = t % 7;                        // conv1 mapping
  int nn2 = t / 140, rr = t % 140, cg = rr / 7, pg = rr % 7;  // conv2 mapping
  float wr[30];
  float s1c = 0.f, sh1c = 0.f;
  if (t < 280) {
    const float* weff = ws + WS_WEFF + c1 * 30;
#pragma unroll
    for (int j = 0; j < 30; ++j) wr[j] = weff[j];
    s1c = ws[WS_S1 + c1];
    sh1c = ws[WS_SH1 + c1];
  }
  // prologue: stage first 2 nodes into xbp[0]
  if (t < 100) {
    int nn = t / 50, q = t % 50;
    float4 v = ((const float4*)(x1 + (b * 1024 + base_n + nn) * 200))[q];
    float vv[4] = {v.x, v.y, v.z, v.w};
#pragma unroll
    for (int m = 0; m < 4; ++m) {
      int j = q * 4 + m;
      xbp[0][nn * 320 + (j / 5) * 8 + (j % 5)] = vv[m];
    }
  }
  __syncthreads();
  float acc[2][5] = {};
  for (int it = 0; it < 8; ++it) {
    int n0 = base_n + it * 2;
    int cur = it & 1;
    // stage w2 (single-buffered: prev conv2 done at loop-end barrier)
    const float4* wsrc = (const float4*)(w2t + n0 * 1600);
    for (int i = t; i < 800; i += 320) ((float4*)w2s)[i] = wsrc[i];
    // conv1 + bn1 + elu -> tmpP
    if (t < 280) {
#pragma unroll
      for (int nn = 0; nn < 2; ++nn) {
        float xq[10][5];
        int xb = nn * 320 + wg * 40;
#pragma unroll
        for (int pi = 0; pi < 10; ++pi) {
          float4 v = *(const float4*)&xbp[cur][xb + pi * 8];
          xq[pi][0] = v.x; xq[pi][1] = v.y; xq[pi][2] = v.z; xq[pi][3] = v.w;
          xq[pi][4] = xbp[cur][xb + pi * 8 + 4];
        }
        float e[5];
#pragma unroll
        for (int u = 0; u < 5; ++u) {
          float s = 0.f;
#pragma unroll
          for (int m = 0; m < 6; ++m)
#pragma unroll
            for (int r = 0; r < 5; ++r) s += xq[u + m][r] * wr[m * 5 + r];
          float v = s * s1c + sh1c;
          e[u] = v > 0.f ? v : __expf(v) - 1.f;
        }
        float* tp = &tmpP[nn * 3364 + c1 * 84 + wg * 12];
        *(float4*)tp = make_float4(e[0], e[1], e[2], e[3]);
        tp[4] = e[4];
      }
    }
    __syncthreads();
    // stage next iter's x while conv2 runs
    if (it < 7 && t < 100) {
      int nn = t / 50, q = t % 50;
      float4 v = ((const float4*)(x1 + (b * 1024 + n0 + 2 + nn) * 200))[q];
      float vv[4] = {v.x, v.y, v.z, v.w};
#pragma unroll
      for (int m = 0; m < 4; ++m) {
        int j = q * 4 + m;
        xbp[cur ^ 1][nn * 320 + (j / 5) * 8 + (j % 5)] = vv[m];
      }
    }
    // conv2 accumulate
    if (t < 280) {
      const float* tb = &tmpP[nn2 * 3364 + pg * 12];
      const float* wb = &w2s[nn2 * 1600 + cg * 2];
#pragma unroll 4
      for (int cc = 0; cc < 40; ++cc) {
        float4 tv = *(const float4*)&tb[cc * 84];
        float t4 = tb[cc * 84 + 4];
        float2 wv = *(const float2*)&wb[cc * 40];
        acc[0][0] += tv.x * wv.x; acc[0][1] += tv.y * wv.x; acc[0][2] += tv.z * wv.x;
        acc[0][3] += tv.w * wv.x; acc[0][4] += t4 * wv.x;
        acc[1][0] += tv.x * wv.y; acc[1][1] += tv.y * wv.y; acc[1][2] += tv.z * wv.y;
        acc[1][3] += tv.w * wv.y; acc[1][4] += t4 * wv.y;
      }
    }
    __syncthreads();
  }
  // reduce the 2 nn2 halves via tmpP, write one partial per (b,nt)
  if (t < 280) {
#pragma unroll
    for (int oi = 0; oi < 2; ++oi)
#pragma unroll
      for (int u = 0; u < 5; ++u)
        tmpP[nn2 * 1400 + (cg * 2 + oi) * 35 + pg * 5 + u] = acc[oi][u];
  }
  __syncthreads();
  float* dst = y3p + (b * 64 + nt) * 1400;
  for (int idx = t; idx < 1400; idx += 320)
    dst[idx] = tmpP[idx] + tmpP[1400 + idx];
}

// ---------------- k4a: reduce 64 partials + bn2 + elu -> y4 ----------------
__global__ __launch_bounds__(256) void k4a_red(const float* __restrict__ y3p,
                                               const float* __restrict__ ws,
                                               float* __restrict__ y4) {
  int t = threadIdx.x;
  if (t >= 200) return;
  int b = blockIdx.x;
  int idx = blockIdx.y * 200 + t;
  float s = 0.f;
#pragma unroll 4
  for (int q = 0; q < 64; ++q) s += y3p[(b * 64 + q) * 1400 + idx];
  int o = idx / 35;
  float v = s * ws[WS_S2 + o] + ws[WS_SH2 + o];
  y4[b * 1400 + idx] = v > 0.f ? v : __expf(v) - 1.f;
}

// ---------------- k4b: projc + rearrange -> y5 ----------------
__global__ __launch_bounds__(256) void k4b_proj(const float* __restrict__ y4,
                                                const float* __restrict__ projc_w,
                                                const float* __restrict__ projc_b,
                                                float* __restrict__ y5) {
  __shared__ __align__(16) float tls[1400];
  int t = threadIdx.x, b = blockIdx.x;
  for (int i = t; i < 350; i += 256)
    ((float4*)tls)[i] = ((const float4*)(y4 + b * 1400))[i];
  __syncthreads();
  for (int idx = t; idx < 1400; idx += 256) {
    int p = idx / 40, e = idx % 40;
    float acc = projc_b[e];
    for (int o = 0; o < 40; ++o) acc += tls[o * 35 + p] * projc_w[e * 40 + o];
    y5[b * 1400 + idx] = acc;
  }
}

// ---------------- k5: split-K FC1 partials (224 blocks) ----------------
__global__ __launch_bounds__(256) void k5_fc1(const float* __restrict__ y5,
                                              const float* __restrict__ W1,
                                              float* __restrict__ zp) {
  __shared__ __align__(16) float yls[3200];  // 16 b x 200 k
  int t = threadIdx.x;
  int nc = blockIdx.x, kc = blockIdx.y;  // (32, 7)
  for (int i = t; i < 800; i += 256) {
    int bb = i / 50, q = i % 50;
    ((float4*)yls)[bb * 50 + q] = *(const float4*)(y5 + bb * 1400 + kc * 200 + q * 4);
  }
  __syncthreads();
  int nl = t & 31, bg = t >> 5;  // bg 0..7 -> 2 b each
  int n = nc * 32 + nl;
  float acc0 = 0.f, acc1 = 0.f;
  const float* y0 = yls + (bg * 2) * 200;
  const float* y1 = yls + (bg * 2 + 1) * 200;
  for (int k = 0; k < 200; ++k) {
    float w = W1[(kc * 200 + k) * 1024 + n];
    acc0 += y0[k] * w;
    acc1 += y1[k] * w;
  }
  zp[(kc * 16 + bg * 2) * 1024 + n] = acc0;
  zp[(kc * 16 + bg * 2 + 1) * 1024 + n] = acc1;
}

// ---------------- k5b: reduce FC1 partials + bias; z, gelu(z) ----------------
__global__ __launch_bounds__(256) void k5b_red(const float* __restrict__ zp,
                                               const float* __restrict__ b1,
                                               float* __restrict__ z, float* __restrict__ g) {
  int gid = blockIdx.x * 256 + threadIdx.x;
  int b = gid >> 10, n = gid & 1023;
  float s = b1[n];
#pragma unroll
  for (int kc = 0; kc < 7; ++kc) s += zp[(kc * 16 + b) * 1024 + n];
  z[gid] = s;
  g[gid] = 0.5f * s * (1.f + erff(s * 0.70710678f));
}

// ---------------- k6: split-K FC2 partials (256 blocks) ----------------
__global__ __launch_bounds__(256) void k6_fc2(const float* __restrict__ g,
                                              const float* __restrict__ W2,
                                              float* __restrict__ z2p) {
  __shared__ __align__(16) float gls[2048];  // 16 b x 128 k
  int t = threadIdx.x;
  int nc = blockIdx.x, kc = blockIdx.y;  // (32, 8)
  for (int i = t; i < 512; i += 256) {
    int bb = i / 32, q = i % 32;
    ((float4*)gls)[bb * 32 + q] = *(const float4*)(g + bb * 1024 + kc * 128 + q * 4);
  }
  __syncthreads();
  int nl = t & 31, bg = t >> 5;
  int n = nc * 32 + nl;
  float acc0 = 0.f, acc1 = 0.f;
  const float* g0 = gls + (bg * 2) * 128;
  const float* g1 = gls + (bg * 2 + 1) * 128;
  for (int k = 0; k < 128; ++k) {
    float w = W2[(kc * 128 + k) * 1024 + n];
    acc0 += g0[k] * w;
    acc1 += g1[k] * w;
  }
  z2p[(kc * 16 + bg * 2) * 1024 + n] = acc0;
  z2p[(kc * 16 + bg * 2 + 1) * 1024 + n] = acc1;
}

// ---------------- k7: reduce FC2 partials + residual + LayerNorm ----------------
__global__ __launch_bounds__(256) void k7_ln(const float* __restrict__ z,
                                             const float* __restrict__ z2p,
                                             const float* __restrict__ b2,
                                             const float* __restrict__ ln_g,
                                             const float* __restrict__ ln_b,
                                             float* __restrict__ out) {
  __shared__ float r1[256], r2[256];
  int t = threadIdx.x, b = blockIdx.x;
  float4 v = *(const float4*)(z + b * 1024 + t * 4);
  float4 bb2 = *(const float4*)(b2 + t * 4);
  v.x += bb2.x; v.y += bb2.y; v.z += bb2.z; v.w += bb2.w;
#pragma unroll
  for (int kc = 0; kc < 8; ++kc) {
    float4 p = *(const float4*)(z2p + (kc * 16 + b) * 1024 + t * 4);
    v.x += p.x; v.y += p.y; v.z += p.z; v.w += p.w;
  }
  r1[t] = v.x + v.y + v.z + v.w;
  r2[t] = v.x * v.x + v.y * v.y + v.z * v.z + v.w * v.w;
  __syncthreads();
  for (int s = 128; s > 0; s >>= 1) {
    if (t < s) {
      r1[t] += r1[t + s];
      r2[t] += r2[t + s];
    }
    __syncthreads();
  }
  float mu = r1[0] * (1.f / 1024.f);
  float var = r2[0] * (1.f / 1024.f) - mu * mu;
  float rstd = rsqrtf(var + 1e-5f);
  float4 gg = *(const float4*)(ln_g + t * 4);
  float4 bb = *(const float4*)(ln_b + t * 4);
  float4 o;
  o.x = (v.x - mu) * rstd * gg.x + bb.x;
  o.y = (v.y - mu) * rstd * gg.y + bb.y;
  o.z = (v.z - mu) * rstd * gg.z + bb.z;
  o.w = (v.w - mu) * rstd * gg.w + bb.w;
  *(float4*)(out + b * 1024 + t * 4) = o;
}

extern "C" void kernel_launch(void* const* d_in, const int* in_sizes, int n_in,
                              void* d_out, int out_size, void* d_ws, size_t ws_size,
                              hipStream_t stream) {
  (void)in_sizes; (void)n_in; (void)out_size; (void)ws_size;
  const float* x       = (const float*)d_in[0];
  const float* gat_W   = (const float*)d_in[1];
  const float* att_src = (const float*)d_in[2];
  const float* att_dst = (const float*)d_in[3];
  const float* gat_b   = (const float*)d_in[4];
  const float* conv1_w = (const float*)d_in[5];
  const float* conv2_w = (const float*)d_in[11];
  const float* projc_w = (const float*)d_in[17];
  const float* projc_b = (const float*)d_in[18];
  const float* W1      = (const float*)d_in[19];
  const float* b1      = (const float*)d_in[20];
  const float* W2      = (const float*)d_in[21];
  const float* b2      = (const float*)d_in[22];
  const float* ln_g    = (const float*)d_in[23];
  const float* ln_b    = (const float*)d_in[24];
  float* ws  = (float*)d_ws;
  float* out = (float*)d_out;

  hipLaunchKernelGGL(k0_prep, dim3(201), dim3(256), 0, stream, gat_W, conv1_w,
                     (const float*)d_in[6], (const float*)d_in[7], (const float*)d_in[8],
                     (const float*)d_in[9], (const float*)d_in[10], (const float*)d_in[12],
                     (const float*)d_in[13], (const float*)d_in[14], (const float*)d_in[15],
                     (const float*)d_in[16], ws);
  hipLaunchKernelGGL(k0b_w2t, dim3(50, 16), dim3(256), 0, stream, conv2_w, ws + WS_W2T);
  hipLaunchKernelGGL(k1_gemm_h, dim3(256, 4), dim3(256), 0, stream, x, ws + WS_WPAD, gat_b,
                     ws + WS_H, ws + WS_X1);
  hipLaunchKernelGGL(k1b_scores, dim3(4), dim3(256), 0, stream, ws + WS_H, att_src, att_dst,
                     ws + WS_AS, ws + WS_AD);
  hipLaunchKernelGGL(k1c_max, dim3(1), dim3(256), 0, stream, ws + WS_AS, ws + WS_MAXS);
  hipLaunchKernelGGL(kP, dim3(1024), dim3(256), 0, stream, ws + WS_AS, ws + WS_AD,
                     ws + WS_MAXS, ws + WS_P);
  hipLaunchKernelGGL(kAttn, dim3(16, 4, 8), dim3(256), 0, stream, ws + WS_P, ws + WS_H,
                     ws + WS_AP);
  hipLaunchKernelGGL(kAttnRed, dim3(1024), dim3(256), 0, stream, ws + WS_AP, x, gat_b,
                     ws + WS_X1);
  hipLaunchKernelGGL(k3_conv, dim3(16, 64), dim3(320), 0, stream, ws + WS_X1, ws + WS_W2T,
                     ws, ws + WS_Y3P);
  hipLaunchKernelGGL(k4a_red, dim3(16, 7), dim3(256), 0, stream, ws + WS_Y3P, ws, ws + WS_Y4);
  hipLaunchKernelGGL(k4b_proj, dim3(16), dim3(256), 0, stream, ws + WS_Y4, projc_w, projc_b,
                     ws + WS_Y5);
  hipLaunchKernelGGL(k5_fc1, dim3(32, 7), dim3(256), 0, stream, ws + WS_Y5, W1, ws + WS_ZP);
  hipLaunchKernelGGL(k5b_red, dim3(64), dim3(256), 0, stream, ws + WS_ZP, b1, ws + WS_Z,
                     ws + WS_G);
  hipLaunchKernelGGL(k6_fc2, dim3(32, 8), dim3(256), 0, stream, ws + WS_G, W2, ws + WS_Z2P);
  hipLaunchKernelGGL(k7_ln, dim3(16), dim3(256), 0, stream, ws + WS_Z, ws + WS_Z2P, b2,
                     ln_g, ln_b, out);
}

// Round 5
// 366.292 us; speedup vs baseline: 1.6389x; 1.6389x over previous
//
#include <hip/hip_runtime.h>
#include <math.h>

// ---------------- workspace layout (float offsets) ----------------
#define WS_X1    0                    // 16384*200
#define WS_WPAD  3276800              // 200*256
#define WS_W2T   3328000              // 1024*1600  [n][c*40+o]
#define WS_AS    4966400              // 1024
#define WS_AD    4967424              // 1024
#define WS_MAXS  4968448              // 16
#define WS_WEFF  4968464              // 40*30
#define WS_S1    4969664              // 40
#define WS_SH1   4969704              // 40
#define WS_S2    4969744              // 40
#define WS_SH2   4969784              // 40
#define WS_H     4970496              // 1024*256
#define WS_P     5232640              // 1024*1024 normalized softmax P
#define WS_AP    6281216              // 8*1024*256 attention split-K partials
#define WS_Y3P   WS_P                 // 16*64*1400 (overlays P+AP head; both dead by k3)
#define WS_Y4    8378368              // 16*1400
#define WS_Y5    8400768              // 16*1400
#define WS_Z     8423168              // 16*1024
#define WS_G     8439552              // 16*1024
#define WS_ZP    8455936              // 7*16*1024
#define WS_Z2P   8570624              // 8*16*1024
// end 8,701,696 floats = 34.8 MB (< 36.7 MB proven)

// ---------------- k0: parameter prep ----------------
__global__ __launch_bounds__(256) void k0_prep(const float* __restrict__ gat_W,
                        const float* __restrict__ conv1_w, const float* __restrict__ conv1_b,
                        const float* __restrict__ bn1_g, const float* __restrict__ bn1_b,
                        const float* __restrict__ bn1_m, const float* __restrict__ bn1_v,
                        const float* __restrict__ conv2_b,
                        const float* __restrict__ bn2_g, const float* __restrict__ bn2_b,
                        const float* __restrict__ bn2_m, const float* __restrict__ bn2_v,
                        float* __restrict__ ws) {
  int bx = blockIdx.x, t = threadIdx.x;
  if (bx < 200) {
    ws[WS_WPAD + bx * 256 + t] = (t < 200) ? gat_W[bx * 200 + t] : 0.f;
    return;
  }
  if (t < 40) {
    float* weff = ws + WS_WEFF;
    for (int j = 0; j < 30; ++j) {
      float s = 0.f;
      for (int tt = 0; tt < 5; ++tt) {
        int k = j - tt;
        if (k >= 0 && k < 26) s += conv1_w[t * 26 + k];
      }
      weff[t * 30 + j] = s * 0.2f;
    }
    float s1 = bn1_g[t] * rsqrtf(bn1_v[t] + 1e-5f);
    ws[WS_S1 + t] = s1;
    ws[WS_SH1 + t] = bn1_b[t] + (conv1_b[t] - bn1_m[t]) * s1;
    float s2 = bn2_g[t] * rsqrtf(bn2_v[t] + 1e-5f);
    ws[WS_S2 + t] = s2;
    ws[WS_SH2 + t] = bn2_b[t] + (conv2_b[t] - bn2_m[t]) * s2;
  }
}

// ---------------- k0b: LDS tile transpose conv2_w (o,c,n) -> w2t[n][c*40+o] ----------------
__global__ __launch_bounds__(256) void k0b_w2t(const float* __restrict__ w2,
                                               float* __restrict__ w2t) {
  __shared__ float tile[32][65];
  int jt = blockIdx.x * 32;    // j = c*40+o, 50 tiles
  int n0 = blockIdx.y * 64;    // 16 tiles
  int t = threadIdx.x;
  for (int i = t; i < 2048; i += 256) {
    int jr = i >> 6, n = i & 63;
    int j = jt + jr;
    int o = j % 40, c = j / 40;
    tile[jr][n] = w2[(o * 40 + c) * 1024 + n0 + n];
  }
  __syncthreads();
  for (int i = t; i < 2048; i += 256) {
    int nr = i >> 5, j = i & 31;
    w2t[(n0 + nr) * 1600 + jt + j] = tile[j][nr];
  }
}

// ---------------- k1: h = x @ wpad; rows>=1024 fused into x1 ----------------
__global__ __launch_bounds__(256) void k1_gemm_h(const float* __restrict__ x,
                                                 const float* __restrict__ wpad,
                                                 const float* __restrict__ gat_b,
                                                 float* __restrict__ h,
                                                 float* __restrict__ x1) {
  __shared__ __align__(16) float As[8][64];
  __shared__ __align__(16) float Bs[8][64];
  int t = threadIdx.x;
  int tm = t & 15, tn = t >> 4;
  int row0 = blockIdx.x * 64;
  int col0 = blockIdx.y * 64;
  float acc[4][4] = {};
  for (int k0 = 0; k0 < 200; k0 += 8) {
    for (int i = t; i < 512; i += 256) {
      int m = i >> 3, k = i & 7;
      As[k][m] = x[(row0 + m) * 200 + k0 + k];
    }
    for (int i = t; i < 512; i += 256) {
      int k = i >> 6, n = i & 63;
      Bs[k][n] = wpad[(k0 + k) * 256 + col0 + n];
    }
    __syncthreads();
#pragma unroll
    for (int k = 0; k < 8; ++k) {
      float4 a = *(const float4*)&As[k][tm * 4];
      float4 bq = *(const float4*)&Bs[k][tn * 4];
      float av[4] = {a.x, a.y, a.z, a.w};
      float bv[4] = {bq.x, bq.y, bq.z, bq.w};
#pragma unroll
      for (int i = 0; i < 4; ++i)
#pragma unroll
        for (int j = 0; j < 4; ++j) acc[i][j] += av[i] * bv[j];
    }
    __syncthreads();
  }
  if (row0 < 1024) {
#pragma unroll
    for (int i = 0; i < 4; ++i)
#pragma unroll
      for (int j = 0; j < 4; ++j)
        h[(row0 + tm * 4 + i) * 256 + col0 + tn * 4 + j] = acc[i][j];
  } else {
    int col = col0 + tn * 4;
    if (col < 200) {
      float4 gb = *(const float4*)(gat_b + col);
#pragma unroll
      for (int i = 0; i < 4; ++i) {
        int row = row0 + tm * 4 + i;
        float4 xv = *(const float4*)(x + row * 200 + col);
        float4 o;
        o.x = xv.x + acc[i][0] + gb.x;
        o.y = xv.y + acc[i][1] + gb.y;
        o.z = xv.z + acc[i][2] + gb.z;
        o.w = xv.w + acc[i][3] + gb.w;
        *(float4*)(x1 + row * 200 + col) = o;
      }
    }
  }
}

// ---------------- k1b: attention scores ----------------
__global__ void k1b_scores(const float* __restrict__ h, const float* __restrict__ att_src,
                           const float* __restrict__ att_dst, float* __restrict__ as_,
                           float* __restrict__ ad_) {
  int r = blockIdx.x * 256 + threadIdx.x;
  const float* hr = h + r * 256;
  float s = 0.f, d = 0.f;
  for (int f = 0; f < 200; ++f) {
    float v = hr[f];
    s += v * att_src[f];
    d += v * att_dst[f];
  }
  as_[r] = s;
  ad_[r] = d;
}

// ---------------- k1c: max over a_s ----------------
__global__ void k1c_max(const float* __restrict__ as_, float* __restrict__ maxs) {
  __shared__ float rb[256];
  int t = threadIdx.x;
  float m = -1e30f;
  for (int j = t; j < 1024; j += 256) m = fmaxf(m, as_[j]);
  rb[t] = m;
  __syncthreads();
  for (int s = 128; s > 0; s >>= 1) {
    if (t < s) rb[t] = fmaxf(rb[t], rb[t + s]);
    __syncthreads();
  }
  if (t == 0) maxs[0] = rb[0];
}

// ---------------- kP: normalized softmax P ----------------
__global__ __launch_bounds__(256) void kP(const float* __restrict__ as_,
                                          const float* __restrict__ ad_,
                                          const float* __restrict__ maxs_p,
                                          float* __restrict__ P) {
  __shared__ float rb[256];
  int t = threadIdx.x, i = blockIdx.x;
  float ad = ad_[i];
  float mv = maxs_p[0] + ad;
  float M = mv >= 0.f ? mv : 0.2f * mv;
  float p[4];
  float s = 0.f;
#pragma unroll
  for (int q = 0; q < 4; ++q) {
    float v = as_[q * 256 + t] + ad;
    float l = v >= 0.f ? v : 0.2f * v;
    p[q] = __expf(l - M);
    s += p[q];
  }
  rb[t] = s;
  __syncthreads();
  for (int st = 128; st > 0; st >>= 1) {
    if (t < st) rb[t] += rb[t + st];
    __syncthreads();
  }
  float inv = 1.f / rb[0];
#pragma unroll
  for (int q = 0; q < 4; ++q) P[i * 1024 + q * 256 + t] = p[q] * inv;
}

// ---------------- kAttn: split-K GEMM out0 = P @ h (8 K-chunks) ----------------
__global__ __launch_bounds__(256) void kAttn(const float* __restrict__ P,
                                             const float* __restrict__ h,
                                             float* __restrict__ ap) {
  __shared__ __align__(16) float As[8][64];
  __shared__ __align__(16) float Bs[8][64];
  int t = threadIdx.x;
  int tm = t & 15, tn = t >> 4;
  int i0 = blockIdx.x * 64, f0 = blockIdx.y * 64, j0 = blockIdx.z * 128;
  float acc[4][4] = {};
  for (int k0 = 0; k0 < 128; k0 += 8) {
    for (int i = t; i < 512; i += 256) {
      int m = i >> 3, k = i & 7;
      As[k][m] = P[(i0 + m) * 1024 + j0 + k0 + k];
    }
    for (int i = t; i < 512; i += 256) {
      int k = i >> 6, n = i & 63;
      Bs[k][n] = h[(j0 + k0 + k) * 256 + f0 + n];
    }
    __syncthreads();
#pragma unroll
    for (int k = 0; k < 8; ++k) {
      float4 a = *(const float4*)&As[k][tm * 4];
      float4 bq = *(const float4*)&Bs[k][tn * 4];
      float av[4] = {a.x, a.y, a.z, a.w};
      float bv[4] = {bq.x, bq.y, bq.z, bq.w};
#pragma unroll
      for (int i = 0; i < 4; ++i)
#pragma unroll
        for (int j = 0; j < 4; ++j) acc[i][j] += av[i] * bv[j];
    }
    __syncthreads();
  }
#pragma unroll
  for (int i = 0; i < 4; ++i) {
    int r = i0 + tm * 4 + i;
    float4 v = make_float4(acc[i][0], acc[i][1], acc[i][2], acc[i][3]);
    *(float4*)&ap[(blockIdx.z * 1024 + r) * 256 + f0 + tn * 4] = v;
  }
}

// ---------------- kAttnRed: reduce 8 partials + residual -> x1 rows [0,1024) ----------------
__global__ __launch_bounds__(256) void kAttnRed(const float* __restrict__ ap,
                                                const float* __restrict__ x,
                                                const float* __restrict__ gat_b,
                                                float* __restrict__ x1) {
  int t = threadIdx.x, r = blockIdx.x;
  if (t >= 200) return;
  float s = 0.f;
#pragma unroll
  for (int z = 0; z < 8; ++z) s += ap[(z * 1024 + r) * 256 + t];
  x1[r * 200 + t] = x[r * 200 + t] + s + gat_b[t];
}

// ---------------- k3: fused conv1+bn1+elu+conv2; 2 nodes/iter, high TLP ----------------
// grid (16 b, 64 nt), block 320. Each block: 16 nodes, 8 iters x 2 nodes.
// LDS 45 KB; launch_bounds (320,2): VGPR ~124-128 (NO SPILL — (320,4) forced
// VGPR=64 and spilled xq[10][5] to scratch: 550 MB HBM traffic, 3x slowdown).
// At <=128 VGPR: 16 waves/CU; 3 blocks x 45KB = 135KB < 160KB -> 3 blocks/CU.
__global__ __launch_bounds__(320, 2) void k3_conv(const float* __restrict__ x1,
                                                  const float* __restrict__ w2t,
                                                  const float* __restrict__ ws,
                                                  float* __restrict__ y3p) {
  __shared__ __align__(16) float xbp[2][640];   // dbuf: 2 nodes x 40 windows x 8
  __shared__ __align__(16) float w2s[3200];     // 2 node rows of w2t
  __shared__ __align__(16) float tmpP[6728];    // 2 x 3364, stride 84/12 conflict-padded
  int t = threadIdx.x;
  int b = blockIdx.x, nt = blockIdx.y;
  int base_n = nt * 16;
  int c1 = t / 7, wg = t % 7;                        // conv1 mapping
  int nn2 = t / 140, rr = t % 140, cg = rr / 7, pg = rr % 7;  // conv2 mapping
  float wr[30];
  float s1c = 0.f, sh1c = 0.f;
  if (t < 280) {
    const float* weff = ws + WS_WEFF + c1 * 30;
#pragma unroll
    for (int j = 0; j < 30; ++j) wr[j] = weff[j];
    s1c = ws[WS_S1 + c1];
    sh1c = ws[WS_SH1 + c1];
  }
  // prologue: stage first 2 nodes into xbp[0]
  if (t < 100) {
    int nn = t / 50, q = t % 50;
    float4 v = ((const float4*)(x1 + (b * 1024 + base_n + nn) * 200))[q];
    float vv[4] = {v.x, v.y, v.z, v.w};
#pragma unroll
    for (int m = 0; m < 4; ++m) {
      int j = q * 4 + m;
      xbp[0][nn * 320 + (j / 5) * 8 + (j % 5)] = vv[m];
    }
  }
  __syncthreads();
  float acc[2][5] = {};
  for (int it = 0; it < 8; ++it) {
    int n0 = base_n + it * 2;
    int cur = it & 1;
    // stage w2 (single-buffered: prev conv2 done at loop-end barrier)
    const float4* wsrc = (const float4*)(w2t + n0 * 1600);
    for (int i = t; i < 800; i += 320) ((float4*)w2s)[i] = wsrc[i];
    // conv1 + bn1 + elu -> tmpP
    if (t < 280) {
#pragma unroll
      for (int nn = 0; nn < 2; ++nn) {
        float xq[10][5];
        int xb = nn * 320 + wg * 40;
#pragma unroll
        for (int pi = 0; pi < 10; ++pi) {
          float4 v = *(const float4*)&xbp[cur][xb + pi * 8];
          xq[pi][0] = v.x; xq[pi][1] = v.y; xq[pi][2] = v.z; xq[pi][3] = v.w;
          xq[pi][4] = xbp[cur][xb + pi * 8 + 4];
        }
        float e[5];
#pragma unroll
        for (int u = 0; u < 5; ++u) {
          float s = 0.f;
#pragma unroll
          for (int m = 0; m < 6; ++m)
#pragma unroll
            for (int r = 0; r < 5; ++r) s += xq[u + m][r] * wr[m * 5 + r];
          float v = s * s1c + sh1c;
          e[u] = v > 0.f ? v : __expf(v) - 1.f;
        }
        float* tp = &tmpP[nn * 3364 + c1 * 84 + wg * 12];
        *(float4*)tp = make_float4(e[0], e[1], e[2], e[3]);
        tp[4] = e[4];
      }
    }
    __syncthreads();
    // stage next iter's x while conv2 runs
    if (it < 7 && t < 100) {
      int nn = t / 50, q = t % 50;
      float4 v = ((const float4*)(x1 + (b * 1024 + n0 + 2 + nn) * 200))[q];
      float vv[4] = {v.x, v.y, v.z, v.w};
#pragma unroll
      for (int m = 0; m < 4; ++m) {
        int j = q * 4 + m;
        xbp[cur ^ 1][nn * 320 + (j / 5) * 8 + (j % 5)] = vv[m];
      }
    }
    // conv2 accumulate
    if (t < 280) {
      const float* tb = &tmpP[nn2 * 3364 + pg * 12];
      const float* wb = &w2s[nn2 * 1600 + cg * 2];
#pragma unroll 4
      for (int cc = 0; cc < 40; ++cc) {
        float4 tv = *(const float4*)&tb[cc * 84];
        float t4 = tb[cc * 84 + 4];
        float2 wv = *(const float2*)&wb[cc * 40];
        acc[0][0] += tv.x * wv.x; acc[0][1] += tv.y * wv.x; acc[0][2] += tv.z * wv.x;
        acc[0][3] += tv.w * wv.x; acc[0][4] += t4 * wv.x;
        acc[1][0] += tv.x * wv.y; acc[1][1] += tv.y * wv.y; acc[1][2] += tv.z * wv.y;
        acc[1][3] += tv.w * wv.y; acc[1][4] += t4 * wv.y;
      }
    }
    __syncthreads();
  }
  // reduce the 2 nn2 halves via tmpP, write one partial per (b,nt)
  if (t < 280) {
#pragma unroll
    for (int oi = 0; oi < 2; ++oi)
#pragma unroll
      for (int u = 0; u < 5; ++u)
        tmpP[nn2 * 1400 + (cg * 2 + oi) * 35 + pg * 5 + u] = acc[oi][u];
  }
  __syncthreads();
  float* dst = y3p + (b * 64 + nt) * 1400;
  for (int idx = t; idx < 1400; idx += 320)
    dst[idx] = tmpP[idx] + tmpP[1400 + idx];
}

// ---------------- k4a: reduce 64 partials + bn2 + elu -> y4 ----------------
__global__ __launch_bounds__(256) void k4a_red(const float* __restrict__ y3p,
                                               const float* __restrict__ ws,
                                               float* __restrict__ y4) {
  int t = threadIdx.x;
  if (t >= 200) return;
  int b = blockIdx.x;
  int idx = blockIdx.y * 200 + t;
  float s = 0.f;
#pragma unroll 4
  for (int q = 0; q < 64; ++q) s += y3p[(b * 64 + q) * 1400 + idx];
  int o = idx / 35;
  float v = s * ws[WS_S2 + o] + ws[WS_SH2 + o];
  y4[b * 1400 + idx] = v > 0.f ? v : __expf(v) - 1.f;
}

// ---------------- k4b: projc + rearrange -> y5 ----------------
__global__ __launch_bounds__(256) void k4b_proj(const float* __restrict__ y4,
                                                const float* __restrict__ projc_w,
                                                const float* __restrict__ projc_b,
                                                float* __restrict__ y5) {
  __shared__ __align__(16) float tls[1400];
  int t = threadIdx.x, b = blockIdx.x;
  for (int i = t; i < 350; i += 256)
    ((float4*)tls)[i] = ((const float4*)(y4 + b * 1400))[i];
  __syncthreads();
  for (int idx = t; idx < 1400; idx += 256) {
    int p = idx / 40, e = idx % 40;
    float acc = projc_b[e];
    for (int o = 0; o < 40; ++o) acc += tls[o * 35 + p] * projc_w[e * 40 + o];
    y5[b * 1400 + idx] = acc;
  }
}

// ---------------- k5: split-K FC1 partials (224 blocks) ----------------
__global__ __launch_bounds__(256) void k5_fc1(const float* __restrict__ y5,
                                              const float* __restrict__ W1,
                                              float* __restrict__ zp) {
  __shared__ __align__(16) float yls[3200];  // 16 b x 200 k
  int t = threadIdx.x;
  int nc = blockIdx.x, kc = blockIdx.y;  // (32, 7)
  for (int i = t; i < 800; i += 256) {
    int bb = i / 50, q = i % 50;
    ((float4*)yls)[bb * 50 + q] = *(const float4*)(y5 + bb * 1400 + kc * 200 + q * 4);
  }
  __syncthreads();
  int nl = t & 31, bg = t >> 5;  // bg 0..7 -> 2 b each
  int n = nc * 32 + nl;
  float acc0 = 0.f, acc1 = 0.f;
  const float* y0 = yls + (bg * 2) * 200;
  const float* y1 = yls + (bg * 2 + 1) * 200;
  for (int k = 0; k < 200; ++k) {
    float w = W1[(kc * 200 + k) * 1024 + n];
    acc0 += y0[k] * w;
    acc1 += y1[k] * w;
  }
  zp[(kc * 16 + bg * 2) * 1024 + n] = acc0;
  zp[(kc * 16 + bg * 2 + 1) * 1024 + n] = acc1;
}

// ---------------- k5b: reduce FC1 partials + bias; z, gelu(z) ----------------
__global__ __launch_bounds__(256) void k5b_red(const float* __restrict__ zp,
                                               const float* __restrict__ b1,
                                               float* __restrict__ z, float* __restrict__ g) {
  int gid = blockIdx.x * 256 + threadIdx.x;
  int b = gid >> 10, n = gid & 1023;
  float s = b1[n];
#pragma unroll
  for (int kc = 0; kc < 7; ++kc) s += zp[(kc * 16 + b) * 1024 + n];
  z[gid] = s;
  g[gid] = 0.5f * s * (1.f + erff(s * 0.70710678f));
}

// ---------------- k6: split-K FC2 partials (256 blocks) ----------------
__global__ __launch_bounds__(256) void k6_fc2(const float* __restrict__ g,
                                              const float* __restrict__ W2,
                                              float* __restrict__ z2p) {
  __shared__ __align__(16) float gls[2048];  // 16 b x 128 k
  int t = threadIdx.x;
  int nc = blockIdx.x, kc = blockIdx.y;  // (32, 8)
  for (int i = t; i < 512; i += 256) {
    int bb = i / 32, q = i % 32;
    ((float4*)gls)[bb * 32 + q] = *(const float4*)(g + bb * 1024 + kc * 128 + q * 4);
  }
  __syncthreads();
  int nl = t & 31, bg = t >> 5;
  int n = nc * 32 + nl;
  float acc0 = 0.f, acc1 = 0.f;
  const float* g0 = gls + (bg * 2) * 128;
  const float* g1 = gls + (bg * 2 + 1) * 128;
  for (int k = 0; k < 128; ++k) {
    float w = W2[(kc * 128 + k) * 1024 + n];
    acc0 += g0[k] * w;
    acc1 += g1[k] * w;
  }
  z2p[(kc * 16 + bg * 2) * 1024 + n] = acc0;
  z2p[(kc * 16 + bg * 2 + 1) * 1024 + n] = acc1;
}

// ---------------- k7: reduce FC2 partials + residual + LayerNorm ----------------
__global__ __launch_bounds__(256) void k7_ln(const float* __restrict__ z,
                                             const float* __restrict__ z2p,
                                             const float* __restrict__ b2,
                                             const float* __restrict__ ln_g,
                                             const float* __restrict__ ln_b,
                                             float* __restrict__ out) {
  __shared__ float r1[256], r2[256];
  int t = threadIdx.x, b = blockIdx.x;
  float4 v = *(const float4*)(z + b * 1024 + t * 4);
  float4 bb2 = *(const float4*)(b2 + t * 4);
  v.x += bb2.x; v.y += bb2.y; v.z += bb2.z; v.w += bb2.w;
#pragma unroll
  for (int kc = 0; kc < 8; ++kc) {
    float4 p = *(const float4*)(z2p + (kc * 16 + b) * 1024 + t * 4);
    v.x += p.x; v.y += p.y; v.z += p.z; v.w += p.w;
  }
  r1[t] = v.x + v.y + v.z + v.w;
  r2[t] = v.x * v.x + v.y * v.y + v.z * v.z + v.w * v.w;
  __syncthreads();
  for (int s = 128; s > 0; s >>= 1) {
    if (t < s) {
      r1[t] += r1[t + s];
      r2[t] += r2[t + s];
    }
    __syncthreads();
  }
  float mu = r1[0] * (1.f / 1024.f);
  float var = r2[0] * (1.f / 1024.f) - mu * mu;
  float rstd = rsqrtf(var + 1e-5f);
  float4 gg = *(const float4*)(ln_g + t * 4);
  float4 bb = *(const float4*)(ln_b + t * 4);
  float4 o;
  o.x = (v.x - mu) * rstd * gg.x + bb.x;
  o.y = (v.y - mu) * rstd * gg.y + bb.y;
  o.z = (v.z - mu) * rstd * gg.z + bb.z;
  o.w = (v.w - mu) * rstd * gg.w + bb.w;
  *(float4*)(out + b * 1024 + t * 4) = o;
}

extern "C" void kernel_launch(void* const* d_in, const int* in_sizes, int n_in,
                              void* d_out, int out_size, void* d_ws, size_t ws_size,
                              hipStream_t stream) {
  (void)in_sizes; (void)n_in; (void)out_size; (void)ws_size;
  const float* x       = (const float*)d_in[0];
  const float* gat_W   = (const float*)d_in[1];
  const float* att_src = (const float*)d_in[2];
  const float* att_dst = (const float*)d_in[3];
  const float* gat_b   = (const float*)d_in[4];
  const float* conv1_w = (const float*)d_in[5];
  const float* conv2_w = (const float*)d_in[11];
  const float* projc_w = (const float*)d_in[17];
  const float* projc_b = (const float*)d_in[18];
  const float* W1      = (const float*)d_in[19];
  const float* b1      = (const float*)d_in[20];
  const float* W2      = (const float*)d_in[21];
  const float* b2      = (const float*)d_in[22];
  const float* ln_g    = (const float*)d_in[23];
  const float* ln_b    = (const float*)d_in[24];
  float* ws  = (float*)d_ws;
  float* out = (float*)d_out;

  hipLaunchKernelGGL(k0_prep, dim3(201), dim3(256), 0, stream, gat_W, conv1_w,
                     (const float*)d_in[6], (const float*)d_in[7], (const float*)d_in[8],
                     (const float*)d_in[9], (const float*)d_in[10], (const float*)d_in[12],
                     (const float*)d_in[13], (const float*)d_in[14], (const float*)d_in[15],
                     (const float*)d_in[16], ws);
  hipLaunchKernelGGL(k0b_w2t, dim3(50, 16), dim3(256), 0, stream, conv2_w, ws + WS_W2T);
  hipLaunchKernelGGL(k1_gemm_h, dim3(256, 4), dim3(256), 0, stream, x, ws + WS_WPAD, gat_b,
                     ws + WS_H, ws + WS_X1);
  hipLaunchKernelGGL(k1b_scores, dim3(4), dim3(256), 0, stream, ws + WS_H, att_src, att_dst,
                     ws + WS_AS, ws + WS_AD);
  hipLaunchKernelGGL(k1c_max, dim3(1), dim3(256), 0, stream, ws + WS_AS, ws + WS_MAXS);
  hipLaunchKernelGGL(kP, dim3(1024), dim3(256), 0, stream, ws + WS_AS, ws + WS_AD,
                     ws + WS_MAXS, ws + WS_P);
  hipLaunchKernelGGL(kAttn, dim3(16, 4, 8), dim3(256), 0, stream, ws + WS_P, ws + WS_H,
                     ws + WS_AP);
  hipLaunchKernelGGL(kAttnRed, dim3(1024), dim3(256), 0, stream, ws + WS_AP, x, gat_b,
                     ws + WS_X1);
  hipLaunchKernelGGL(k3_conv, dim3(16, 64), dim3(320), 0, stream, ws + WS_X1, ws + WS_W2T,
                     ws, ws + WS_Y3P);
  hipLaunchKernelGGL(k4a_red, dim3(16, 7), dim3(256), 0, stream, ws + WS_Y3P, ws, ws + WS_Y4);
  hipLaunchKernelGGL(k4b_proj, dim3(16), dim3(256), 0, stream, ws + WS_Y4, projc_w, projc_b,
                     ws + WS_Y5);
  hipLaunchKernelGGL(k5_fc1, dim3(32, 7), dim3(256), 0, stream, ws + WS_Y5, W1, ws + WS_ZP);
  hipLaunchKernelGGL(k5b_red, dim3(64), dim3(256), 0, stream, ws + WS_ZP, b1, ws + WS_Z,
                     ws + WS_G);
  hipLaunchKernelGGL(k6_fc2, dim3(32, 8), dim3(256), 0, stream, ws + WS_G, W2, ws + WS_Z2P);
  hipLaunchKernelGGL(k7_ln, dim3(16), dim3(256), 0, stream, ws + WS_Z, ws + WS_Z2P, b2,
                     ln_g, ln_b, out);
}

// Round 6
// 317.309 us; speedup vs baseline: 1.8919x; 1.1544x over previous
//
#include <hip/hip_runtime.h>
#include <math.h>

typedef __attribute__((ext_vector_type(8))) short short8;
typedef __attribute__((ext_vector_type(4))) float f32x4;

__device__ __forceinline__ unsigned f2bf(float f) {
  unsigned u = __float_as_uint(f);
  return (u + 0x7FFFu + ((u >> 16) & 1u)) >> 16;
}
__device__ __forceinline__ unsigned pk2(float lo, float hi) {
  return f2bf(lo) | (f2bf(hi) << 16);
}
__device__ __forceinline__ float bf_lo(unsigned u) { return __uint_as_float(u << 16); }
__device__ __forceinline__ float bf_hi(unsigned u) { return __uint_as_float(u & 0xFFFF0000u); }

// ---------------- workspace layout (float offsets) ----------------
#define WS_X1    0                    // 16384*200
#define WS_W2T   3328000              // 1024*1600  [n][c*40+o] fp32
#define WS_AS    4966400              // 1024
#define WS_AD    4967424              // 1024
#define WS_MAXS  4968448              // 16
#define WS_WEFF  4968464              // 40*30
#define WS_S1    4969664              // 40
#define WS_SH1   4969704              // 40
#define WS_S2    4969744              // 40
#define WS_SH2   4969784              // 40
#define WS_H     4970496              // 1024*256
#define WS_P     5232640              // 1024*1024 normalized softmax P
#define WS_AP    6281216              // 8*1024*256 attention split-K partials
#define WS_Y3P   WS_P                 // 16*32*1400 (overlays P; dead by k3)
#define WS_Y4    8378368              // 16*1400
#define WS_Y5    8400768              // 16*1400
#define WS_ZP    8455936              // 7*16*1024
#define WS_Z2P   8570624              // 8*16*1024
#define WS_WPT   8701696              // 256*224 bf16 = 28672 floats: gat_W^T zero-padded
// end 8,730,368 floats = 34.9 MB (< 36.7 MB proven)

// ---------------- k0: param prep + wpadT bf16 + w2t transpose ----------------
__global__ __launch_bounds__(256) void k0_prep(const float* __restrict__ gat_W,
                        const float* __restrict__ conv1_w, const float* __restrict__ conv1_b,
                        const float* __restrict__ bn1_g, const float* __restrict__ bn1_b,
                        const float* __restrict__ bn1_m, const float* __restrict__ bn1_v,
                        const float* __restrict__ conv2_b,
                        const float* __restrict__ bn2_g, const float* __restrict__ bn2_b,
                        const float* __restrict__ bn2_m, const float* __restrict__ bn2_v,
                        const float* __restrict__ w2,
                        float* __restrict__ ws) {
  int bx = blockIdx.x, t = threadIdx.x;
  if (bx < 224) {
    // wpadT[n][k] bf16 = gat_W[k][n], zero-padded to 256x224
    unsigned short* wpt = (unsigned short*)(ws + WS_WPT);
    int idx = bx * 256 + t;  // n*224 + k
    int n = idx / 224, k = idx % 224;
    float v = (n < 200 && k < 200) ? gat_W[k * 200 + n] : 0.f;
    wpt[idx] = (unsigned short)f2bf(v);
    return;
  }
  if (bx == 224) {
    if (t < 40) {
      float* weff = ws + WS_WEFF;
      for (int j = 0; j < 30; ++j) {
        float s = 0.f;
        for (int tt = 0; tt < 5; ++tt) {
          int k = j - tt;
          if (k >= 0 && k < 26) s += conv1_w[t * 26 + k];
        }
        weff[t * 30 + j] = s * 0.2f;
      }
      float s1 = bn1_g[t] * rsqrtf(bn1_v[t] + 1e-5f);
      ws[WS_S1 + t] = s1;
      ws[WS_SH1 + t] = bn1_b[t] + (conv1_b[t] - bn1_m[t]) * s1;
      float s2 = bn2_g[t] * rsqrtf(bn2_v[t] + 1e-5f);
      ws[WS_S2 + t] = s2;
      ws[WS_SH2 + t] = bn2_b[t] + (conv2_b[t] - bn2_m[t]) * s2;
    }
    return;
  }
  // w2t transpose tiles: q in [0,800)
  __shared__ float tile[32][65];
  int q = bx - 225;
  int jt = (q / 16) * 32;
  int n0 = (q % 16) * 64;
  float* w2t = ws + WS_W2T;
  for (int i = t; i < 2048; i += 256) {
    int jr = i >> 6, n = i & 63;
    int j = jt + jr;
    int o = j % 40, c = j / 40;
    tile[jr][n] = w2[(o * 40 + c) * 1024 + n0 + n];
  }
  __syncthreads();
  for (int i = t; i < 2048; i += 256) {
    int nr = i >> 5, j = i & 31;
    w2t[(n0 + nr) * 1600 + jt + j] = tile[j][nr];
  }
}

// ---------------- k1: MFMA bf16 GEMM h = x @ W (K=200 pad 224) ----------------
// grid (256 m-tiles of 64, 4 n-tiles of 64), block 256 = 4 waves.
// rows<1024 -> h (stride 256); rows>=1024 -> x1 = x + acc + gat_b (cols<200)
__global__ __launch_bounds__(256) void k1_mfma(const float* __restrict__ x,
                                               const unsigned short* __restrict__ wpt,
                                               const float* __restrict__ gat_b,
                                               float* __restrict__ h,
                                               float* __restrict__ x1) {
  __shared__ unsigned short Bt[64 * 232];    // [n][k] bf16, stride 232
  __shared__ unsigned short As[2][64 * 40];  // [m][k32] bf16, stride 40
  int t = threadIdx.x;
  int wave = t >> 6, lane = t & 63;
  int m16 = lane & 15, quad = lane >> 4;
  int row0 = blockIdx.x * 64, n0 = blockIdx.y * 64;
  // stage Bt (whole K)
  for (int i = t; i < 1792; i += 256) {
    int row = i / 28, ch = i % 28;
    *(short8*)&Bt[row * 232 + ch * 8] = *(const short8*)&wpt[(n0 + row) * 224 + ch * 8];
  }
  // stage As step 0
  {
    int m = t >> 2, kq = (t & 3) * 8;
    const float* xr = x + (row0 + m) * 200 + kq;
    float4 a = *(const float4*)xr;
    float4 b = *(const float4*)(xr + 4);
    uint4 pv;
    pv.x = pk2(a.x, a.y); pv.y = pk2(a.z, a.w);
    pv.z = pk2(b.x, b.y); pv.w = pk2(b.z, b.w);
    *(uint4*)&As[0][m * 40 + kq] = pv;
  }
  __syncthreads();
  f32x4 acc0 = {0.f, 0.f, 0.f, 0.f}, acc1 = acc0, acc2 = acc0, acc3 = acc0;
  int buf = 0;
  for (int s = 0; s < 7; ++s) {
    if (s < 6) {
      int m = t >> 2, kq = (t & 3) * 8;
      int kg = (s + 1) * 32 + kq;
      const float* xr = x + (row0 + m) * 200;
      uint4 pv;
      if (kg + 8 <= 200) {
        float4 a = *(const float4*)(xr + kg);
        float4 b = *(const float4*)(xr + kg + 4);
        pv.x = pk2(a.x, a.y); pv.y = pk2(a.z, a.w);
        pv.z = pk2(b.x, b.y); pv.w = pk2(b.z, b.w);
      } else {
        float e[8];
#pragma unroll
        for (int q = 0; q < 8; ++q) e[q] = (kg + q < 200) ? xr[kg + q] : 0.f;
        pv.x = pk2(e[0], e[1]); pv.y = pk2(e[2], e[3]);
        pv.z = pk2(e[4], e[5]); pv.w = pk2(e[6], e[7]);
      }
      *(uint4*)&As[buf ^ 1][m * 40 + kq] = pv;
    }
    short8 af = *(const short8*)&As[buf][(wave * 16 + m16) * 40 + quad * 8];
    int kb = s * 32 + quad * 8;
    short8 b0 = *(const short8*)&Bt[(0 * 16 + m16) * 232 + kb];
    short8 b1 = *(const short8*)&Bt[(1 * 16 + m16) * 232 + kb];
    short8 b2 = *(const short8*)&Bt[(2 * 16 + m16) * 232 + kb];
    short8 b3 = *(const short8*)&Bt[(3 * 16 + m16) * 232 + kb];
    acc0 = __builtin_amdgcn_mfma_f32_16x16x32_bf16(af, b0, acc0, 0, 0, 0);
    acc1 = __builtin_amdgcn_mfma_f32_16x16x32_bf16(af, b1, acc1, 0, 0, 0);
    acc2 = __builtin_amdgcn_mfma_f32_16x16x32_bf16(af, b2, acc2, 0, 0, 0);
    acc3 = __builtin_amdgcn_mfma_f32_16x16x32_bf16(af, b3, acc3, 0, 0, 0);
    __syncthreads();
    buf ^= 1;
  }
  f32x4 accs[4] = {acc0, acc1, acc2, acc3};
  if (blockIdx.x < 16) {
#pragma unroll
    for (int nt = 0; nt < 4; ++nt)
#pragma unroll
      for (int r = 0; r < 4; ++r) {
        int row = row0 + wave * 16 + quad * 4 + r;
        h[row * 256 + n0 + nt * 16 + m16] = accs[nt][r];
      }
  } else {
#pragma unroll
    for (int nt = 0; nt < 4; ++nt) {
      int col = n0 + nt * 16 + m16;
      if (col < 200) {
#pragma unroll
        for (int r = 0; r < 4; ++r) {
          int row = row0 + wave * 16 + quad * 4 + r;
          x1[row * 200 + col] = x[row * 200 + col] + accs[nt][r] + gat_b[col];
        }
      }
    }
  }
}

// ---------------- k1b: attention scores ----------------
__global__ void k1b_scores(const float* __restrict__ h, const float* __restrict__ att_src,
                           const float* __restrict__ att_dst, float* __restrict__ as_,
                           float* __restrict__ ad_) {
  int r = blockIdx.x * 256 + threadIdx.x;
  const float* hr = h + r * 256;
  float s = 0.f, d = 0.f;
  for (int f = 0; f < 200; ++f) {
    float v = hr[f];
    s += v * att_src[f];
    d += v * att_dst[f];
  }
  as_[r] = s;
  ad_[r] = d;
}

// ---------------- k1c: max over a_s ----------------
__global__ void k1c_max(const float* __restrict__ as_, float* __restrict__ maxs) {
  __shared__ float rb[256];
  int t = threadIdx.x;
  float m = -1e30f;
  for (int j = t; j < 1024; j += 256) m = fmaxf(m, as_[j]);
  rb[t] = m;
  __syncthreads();
  for (int s = 128; s > 0; s >>= 1) {
    if (t < s) rb[t] = fmaxf(rb[t], rb[t + s]);
    __syncthreads();
  }
  if (t == 0) maxs[0] = rb[0];
}

// ---------------- kP: normalized softmax P ----------------
__global__ __launch_bounds__(256) void kP(const float* __restrict__ as_,
                                          const float* __restrict__ ad_,
                                          const float* __restrict__ maxs_p,
                                          float* __restrict__ P) {
  __shared__ float rb[256];
  int t = threadIdx.x, i = blockIdx.x;
  float ad = ad_[i];
  float mv = maxs_p[0] + ad;
  float M = mv >= 0.f ? mv : 0.2f * mv;
  float p[4];
  float s = 0.f;
#pragma unroll
  for (int q = 0; q < 4; ++q) {
    float v = as_[q * 256 + t] + ad;
    float l = v >= 0.f ? v : 0.2f * v;
    p[q] = __expf(l - M);
    s += p[q];
  }
  rb[t] = s;
  __syncthreads();
  for (int st = 128; st > 0; st >>= 1) {
    if (t < st) rb[t] += rb[t + st];
    __syncthreads();
  }
  float inv = 1.f / rb[0];
#pragma unroll
  for (int q = 0; q < 4; ++q) P[i * 1024 + q * 256 + t] = p[q] * inv;
}

// ---------------- kAttn: split-K GEMM out0 = P @ h (8 K-chunks) ----------------
__global__ __launch_bounds__(256) void kAttn(const float* __restrict__ P,
                                             const float* __restrict__ h,
                                             float* __restrict__ ap) {
  __shared__ __align__(16) float As2[8][64];
  __shared__ __align__(16) float Bs[8][64];
  int t = threadIdx.x;
  int tm = t & 15, tn = t >> 4;
  int i0 = blockIdx.x * 64, f0 = blockIdx.y * 64, j0 = blockIdx.z * 128;
  float acc[4][4] = {};
  for (int k0 = 0; k0 < 128; k0 += 8) {
    for (int i = t; i < 512; i += 256) {
      int m = i >> 3, k = i & 7;
      As2[k][m] = P[(i0 + m) * 1024 + j0 + k0 + k];
    }
    for (int i = t; i < 512; i += 256) {
      int k = i >> 6, n = i & 63;
      Bs[k][n] = h[(j0 + k0 + k) * 256 + f0 + n];
    }
    __syncthreads();
#pragma unroll
    for (int k = 0; k < 8; ++k) {
      float4 a = *(const float4*)&As2[k][tm * 4];
      float4 bq = *(const float4*)&Bs[k][tn * 4];
      float av[4] = {a.x, a.y, a.z, a.w};
      float bv[4] = {bq.x, bq.y, bq.z, bq.w};
#pragma unroll
      for (int i = 0; i < 4; ++i)
#pragma unroll
        for (int j = 0; j < 4; ++j) acc[i][j] += av[i] * bv[j];
    }
    __syncthreads();
  }
#pragma unroll
  for (int i = 0; i < 4; ++i) {
    int r = i0 + tm * 4 + i;
    float4 v = make_float4(acc[i][0], acc[i][1], acc[i][2], acc[i][3]);
    *(float4*)&ap[(blockIdx.z * 1024 + r) * 256 + f0 + tn * 4] = v;
  }
}

// ---------------- kAttnRed ----------------
__global__ __launch_bounds__(256) void kAttnRed(const float* __restrict__ ap,
                                                const float* __restrict__ x,
                                                const float* __restrict__ gat_b,
                                                float* __restrict__ x1) {
  int t = threadIdx.x, r = blockIdx.x;
  if (t >= 200) return;
  float s = 0.f;
#pragma unroll
  for (int z = 0; z < 8; ++z) s += ap[(z * 1024 + r) * 256 + t];
  x1[r * 200 + t] = x[r * 200 + t] + s + gat_b[t];
}

// ---------------- k3: fused conv1+bn1+elu+conv2; bf16 tmp, 4 nodes/iter ----------------
// grid (16,32), block 320; 8 iters x 4 nodes. LDS ~57.6 KB.
// conv2 inner: 2 LDS insts / 40 MAC (ushort8 tmp + float4 w).
__global__ __launch_bounds__(320, 2) void k3_conv(const float* __restrict__ x1,
                                                  const float* __restrict__ w2t,
                                                  const float* __restrict__ ws,
                                                  float* __restrict__ y3p) {
  __shared__ __align__(16) float xbp[2][1280];       // dbuf: 4 nodes x 40 win x 8
  __shared__ __align__(16) float w2s[6400];          // 4 node rows of w2t (fp32)
  __shared__ __align__(16) unsigned short tmpB[11552];  // 4 nodes x (40c x 72 + 8)
  int t = threadIdx.x;
  int b = blockIdx.x, nt = blockIdx.y;
  int base_n = nt * 32;
  int c1 = t / 7, wg = t % 7;
  int nn2 = t / 70, rr = t % 70, cg = rr / 7, pg = rr % 7;
  float wr[30];
  float s1c = 0.f, sh1c = 0.f;
  if (t < 280) {
    const float* weff = ws + WS_WEFF + c1 * 30;
#pragma unroll
    for (int j = 0; j < 30; ++j) wr[j] = weff[j];
    s1c = ws[WS_S1 + c1];
    sh1c = ws[WS_SH1 + c1];
  }
  // prologue: stage first 4 nodes into xbp[0]
  if (t < 200) {
    int nn = t / 50, q = t % 50;
    float4 v = ((const float4*)(x1 + (b * 1024 + base_n + nn) * 200))[q];
    float vv[4] = {v.x, v.y, v.z, v.w};
#pragma unroll
    for (int m = 0; m < 4; ++m) {
      int j = q * 4 + m;
      xbp[0][nn * 320 + (j / 5) * 8 + (j % 5)] = vv[m];
    }
  }
  __syncthreads();
  float acc[4][5] = {};
  for (int it = 0; it < 8; ++it) {
    int n0 = base_n + it * 4;
    int cur = it & 1;
    // phase 1: stage w2s(it) + conv1 -> tmpB
    {
      const float4* wsrc = (const float4*)(w2t + n0 * 1600);
#pragma unroll
      for (int s = 0; s < 5; ++s) ((float4*)w2s)[t + s * 320] = wsrc[t + s * 320];
    }
    if (t < 280) {
#pragma unroll
      for (int nn = 0; nn < 4; ++nn) {
        float xq[10][5];
        int xb = nn * 320 + wg * 40;
#pragma unroll
        for (int pi = 0; pi < 10; ++pi) {
          float4 v = *(const float4*)&xbp[cur][xb + pi * 8];
          xq[pi][0] = v.x; xq[pi][1] = v.y; xq[pi][2] = v.z; xq[pi][3] = v.w;
          xq[pi][4] = xbp[cur][xb + pi * 8 + 4];
        }
        float e[5];
#pragma unroll
        for (int u = 0; u < 5; ++u) {
          float s = 0.f;
#pragma unroll
          for (int m = 0; m < 6; ++m)
#pragma unroll
            for (int r = 0; r < 5; ++r) s += xq[u + m][r] * wr[m * 5 + r];
          float v = s * s1c + sh1c;
          e[u] = v > 0.f ? v : __expf(v) - 1.f;
        }
        uint4 pv;
        pv.x = pk2(e[0], e[1]); pv.y = pk2(e[2], e[3]);
        pv.z = pk2(e[4], 0.f);  pv.w = 0u;
        *(uint4*)&tmpB[nn * 2888 + c1 * 72 + wg * 8] = pv;
      }
    }
    __syncthreads();
    // phase 2: stage next x + conv2
    if (it < 7 && t < 200) {
      int nn = t / 50, q = t % 50;
      float4 v = ((const float4*)(x1 + (b * 1024 + n0 + 4 + nn) * 200))[q];
      float vv[4] = {v.x, v.y, v.z, v.w};
#pragma unroll
      for (int m = 0; m < 4; ++m) {
        int j = q * 4 + m;
        xbp[cur ^ 1][nn * 320 + (j / 5) * 8 + (j % 5)] = vv[m];
      }
    }
    if (t < 280) {
      const unsigned short* tb = &tmpB[nn2 * 2888 + pg * 8];
      const float* wb = &w2s[nn2 * 1600 + cg * 4];
#pragma unroll 4
      for (int cc = 0; cc < 40; ++cc) {
        uint4 tv = *(const uint4*)&tb[cc * 72];
        float t0 = bf_lo(tv.x), t1 = bf_hi(tv.x);
        float t2 = bf_lo(tv.y), t3 = bf_hi(tv.y);
        float t4 = bf_lo(tv.z);
        float4 wv = *(const float4*)&wb[cc * 40];
        acc[0][0] += t0 * wv.x; acc[0][1] += t1 * wv.x; acc[0][2] += t2 * wv.x;
        acc[0][3] += t3 * wv.x; acc[0][4] += t4 * wv.x;
        acc[1][0] += t0 * wv.y; acc[1][1] += t1 * wv.y; acc[1][2] += t2 * wv.y;
        acc[1][3] += t3 * wv.y; acc[1][4] += t4 * wv.y;
        acc[2][0] += t0 * wv.z; acc[2][1] += t1 * wv.z; acc[2][2] += t2 * wv.z;
        acc[2][3] += t3 * wv.z; acc[2][4] += t4 * wv.z;
        acc[3][0] += t0 * wv.w; acc[3][1] += t1 * wv.w; acc[3][2] += t2 * wv.w;
        acc[3][3] += t3 * wv.w; acc[3][4] += t4 * wv.w;
      }
    }
    __syncthreads();
  }
  // cross-nn2 reduction via w2s (dead now)
  if (t < 280) {
#pragma unroll
    for (int oi = 0; oi < 4; ++oi)
#pragma unroll
      for (int u = 0; u < 5; ++u)
        w2s[nn2 * 1400 + (cg * 4 + oi) * 35 + pg * 5 + u] = acc[oi][u];
  }
  __syncthreads();
  float* dst = y3p + (b * 32 + nt) * 1400;
  for (int idx = t; idx < 1400; idx += 320)
    dst[idx] = w2s[idx] + w2s[1400 + idx] + w2s[2800 + idx] + w2s[4200 + idx];
}

// ---------------- k4a: reduce 32 partials + bn2 + elu -> y4 ----------------
__global__ __launch_bounds__(256) void k4a_red(const float* __restrict__ y3p,
                                               const float* __restrict__ ws,
                                               float* __restrict__ y4) {
  int t = threadIdx.x;
  if (t >= 200) return;
  int b = blockIdx.x;
  int idx = blockIdx.y * 200 + t;
  float s = 0.f;
#pragma unroll 4
  for (int q = 0; q < 32; ++q) s += y3p[(b * 32 + q) * 1400 + idx];
  int o = idx / 35;
  float v = s * ws[WS_S2 + o] + ws[WS_SH2 + o];
  y4[b * 1400 + idx] = v > 0.f ? v : __expf(v) - 1.f;
}

// ---------------- k4b: projc + rearrange -> y5 ----------------
__global__ __launch_bounds__(256) void k4b_proj(const float* __restrict__ y4,
                                                const float* __restrict__ projc_w,
                                                const float* __restrict__ projc_b,
                                                float* __restrict__ y5) {
  __shared__ __align__(16) float tls[1400];
  int t = threadIdx.x, b = blockIdx.x;
  for (int i = t; i < 350; i += 256)
    ((float4*)tls)[i] = ((const float4*)(y4 + b * 1400))[i];
  __syncthreads();
  for (int idx = t; idx < 1400; idx += 256) {
    int p = idx / 40, e = idx % 40;
    float acc = projc_b[e];
    for (int o = 0; o < 40; ++o) acc += tls[o * 35 + p] * projc_w[e * 40 + o];
    y5[b * 1400 + idx] = acc;
  }
}

// ---------------- k5: split-K FC1 partials (224 blocks) ----------------
__global__ __launch_bounds__(256) void k5_fc1(const float* __restrict__ y5,
                                              const float* __restrict__ W1,
                                              float* __restrict__ zp) {
  __shared__ __align__(16) float yls[3200];
  int t = threadIdx.x;
  int nc = blockIdx.x, kc = blockIdx.y;  // (32, 7)
  for (int i = t; i < 800; i += 256) {
    int bb = i / 50, q = i % 50;
    ((float4*)yls)[bb * 50 + q] = *(const float4*)(y5 + bb * 1400 + kc * 200 + q * 4);
  }
  __syncthreads();
  int nl = t & 31, bg = t >> 5;
  int n = nc * 32 + nl;
  float acc0 = 0.f, acc1 = 0.f;
  const float* y0 = yls + (bg * 2) * 200;
  const float* y1 = yls + (bg * 2 + 1) * 200;
  for (int k = 0; k < 200; ++k) {
    float w = W1[(kc * 200 + k) * 1024 + n];
    acc0 += y0[k] * w;
    acc1 += y1[k] * w;
  }
  zp[(kc * 16 + bg * 2) * 1024 + n] = acc0;
  zp[(kc * 16 + bg * 2 + 1) * 1024 + n] = acc1;
}

// ---------------- k6: split-K FC2 partials, gelu(z) on the fly ----------------
__global__ __launch_bounds__(256) void k6_fc2(const float* __restrict__ zp,
                                              const float* __restrict__ b1,
                                              const float* __restrict__ W2,
                                              float* __restrict__ z2p) {
  __shared__ __align__(16) float gls[2048];  // 16 b x 128 k (gelu of z)
  int t = threadIdx.x;
  int nc = blockIdx.x, kc = blockIdx.y;  // (32, 8)
  for (int i = t; i < 2048; i += 256) {
    int bb = i >> 7, kk = i & 127;
    int np = kc * 128 + kk;
    float s = b1[np];
#pragma unroll
    for (int j = 0; j < 7; ++j) s += zp[(j * 16 + bb) * 1024 + np];
    gls[i] = 0.5f * s * (1.f + erff(s * 0.70710678f));
  }
  __syncthreads();
  int nl = t & 31, bg = t >> 5;
  int n = nc * 32 + nl;
  float acc0 = 0.f, acc1 = 0.f;
  const float* g0 = gls + (bg * 2) * 128;
  const float* g1 = gls + (bg * 2 + 1) * 128;
  for (int k = 0; k < 128; ++k) {
    float w = W2[(kc * 128 + k) * 1024 + n];
    acc0 += g0[k] * w;
    acc1 += g1[k] * w;
  }
  z2p[(kc * 16 + bg * 2) * 1024 + n] = acc0;
  z2p[(kc * 16 + bg * 2 + 1) * 1024 + n] = acc1;
}

// ---------------- k7: z recompute + FC2 reduce + residual + LayerNorm ----------------
__global__ __launch_bounds__(256) void k7_ln(const float* __restrict__ zp,
                                             const float* __restrict__ z2p,
                                             const float* __restrict__ b1,
                                             const float* __restrict__ b2,
                                             const float* __restrict__ ln_g,
                                             const float* __restrict__ ln_b,
                                             float* __restrict__ out) {
  __shared__ float r1[256], r2[256];
  int t = threadIdx.x, b = blockIdx.x;
  float4 v = *(const float4*)(b1 + t * 4);
  float4 bb2 = *(const float4*)(b2 + t * 4);
  v.x += bb2.x; v.y += bb2.y; v.z += bb2.z; v.w += bb2.w;
#pragma unroll
  for (int kc = 0; kc < 7; ++kc) {
    float4 p = *(const float4*)(zp + (kc * 16 + b) * 1024 + t * 4);
    v.x += p.x; v.y += p.y; v.z += p.z; v.w += p.w;
  }
#pragma unroll
  for (int kc = 0; kc < 8; ++kc) {
    float4 p = *(const float4*)(z2p + (kc * 16 + b) * 1024 + t * 4);
    v.x += p.x; v.y += p.y; v.z += p.z; v.w += p.w;
  }
  r1[t] = v.x + v.y + v.z + v.w;
  r2[t] = v.x * v.x + v.y * v.y + v.z * v.z + v.w * v.w;
  __syncthreads();
  for (int s = 128; s > 0; s >>= 1) {
    if (t < s) {
      r1[t] += r1[t + s];
      r2[t] += r2[t + s];
    }
    __syncthreads();
  }
  float mu = r1[0] * (1.f / 1024.f);
  float var = r2[0] * (1.f / 1024.f) - mu * mu;
  float rstd = rsqrtf(var + 1e-5f);
  float4 gg = *(const float4*)(ln_g + t * 4);
  float4 bb = *(const float4*)(ln_b + t * 4);
  float4 o;
  o.x = (v.x - mu) * rstd * gg.x + bb.x;
  o.y = (v.y - mu) * rstd * gg.y + bb.y;
  o.z = (v.z - mu) * rstd * gg.z + bb.z;
  o.w = (v.w - mu) * rstd * gg.w + bb.w;
  *(float4*)(out + b * 1024 + t * 4) = o;
}

extern "C" void kernel_launch(void* const* d_in, const int* in_sizes, int n_in,
                              void* d_out, int out_size, void* d_ws, size_t ws_size,
                              hipStream_t stream) {
  (void)in_sizes; (void)n_in; (void)out_size; (void)ws_size;
  const float* x       = (const float*)d_in[0];
  const float* gat_W   = (const float*)d_in[1];
  const float* att_src = (const float*)d_in[2];
  const float* att_dst = (const float*)d_in[3];
  const float* gat_b   = (const float*)d_in[4];
  const float* conv1_w = (const float*)d_in[5];
  const float* conv2_w = (const float*)d_in[11];
  const float* projc_w = (const float*)d_in[17];
  const float* projc_b = (const float*)d_in[18];
  const float* W1      = (const float*)d_in[19];
  const float* b1      = (const float*)d_in[20];
  const float* W2      = (const float*)d_in[21];
  const float* b2      = (const float*)d_in[22];
  const float* ln_g    = (const float*)d_in[23];
  const float* ln_b    = (const float*)d_in[24];
  float* ws  = (float*)d_ws;
  float* out = (float*)d_out;

  hipLaunchKernelGGL(k0_prep, dim3(1025), dim3(256), 0, stream, gat_W, conv1_w,
                     (const float*)d_in[6], (const float*)d_in[7], (const float*)d_in[8],
                     (const float*)d_in[9], (const float*)d_in[10], (const float*)d_in[12],
                     (const float*)d_in[13], (const float*)d_in[14], (const float*)d_in[15],
                     (const float*)d_in[16], conv2_w, ws);
  hipLaunchKernelGGL(k1_mfma, dim3(256, 4), dim3(256), 0, stream, x,
                     (const unsigned short*)(ws + WS_WPT), gat_b, ws + WS_H, ws + WS_X1);
  hipLaunchKernelGGL(k1b_scores, dim3(4), dim3(256), 0, stream, ws + WS_H, att_src, att_dst,
                     ws + WS_AS, ws + WS_AD);
  hipLaunchKernelGGL(k1c_max, dim3(1), dim3(256), 0, stream, ws + WS_AS, ws + WS_MAXS);
  hipLaunchKernelGGL(kP, dim3(1024), dim3(256), 0, stream, ws + WS_AS, ws + WS_AD,
                     ws + WS_MAXS, ws + WS_P);
  hipLaunchKernelGGL(kAttn, dim3(16, 4, 8), dim3(256), 0, stream, ws + WS_P, ws + WS_H,
                     ws + WS_AP);
  hipLaunchKernelGGL(kAttnRed, dim3(1024), dim3(256), 0, stream, ws + WS_AP, x, gat_b,
                     ws + WS_X1);
  hipLaunchKernelGGL(k3_conv, dim3(16, 32), dim3(320), 0, stream, ws + WS_X1, ws + WS_W2T,
                     ws, ws + WS_Y3P);
  hipLaunchKernelGGL(k4a_red, dim3(16, 7), dim3(256), 0, stream, ws + WS_Y3P, ws, ws + WS_Y4);
  hipLaunchKernelGGL(k4b_proj, dim3(16), dim3(256), 0, stream, ws + WS_Y4, projc_w, projc_b,
                     ws + WS_Y5);
  hipLaunchKernelGGL(k5_fc1, dim3(32, 7), dim3(256), 0, stream, ws + WS_Y5, W1, ws + WS_ZP);
  hipLaunchKernelGGL(k6_fc2, dim3(32, 8), dim3(256), 0, stream, ws + WS_ZP, b1, W2,
                     ws + WS_Z2P);
  hipLaunchKernelGGL(k7_ln, dim3(16), dim3(256), 0, stream, ws + WS_ZP, ws + WS_Z2P, b1, b2,
                     ln_g, ln_b, out);
}